// Round 1
// baseline (63.073 us; speedup 1.0000x reference)
//
#include <hip/hip_runtime.h>
#include <math.h>

// Problem sizes (fixed by setup_inputs): B=4096, D=128, K=256, c=1.0
#define B_SZ 4096
#define D_SZ 128
#define K_SZ 256
#define MT   32          // m-tile (batch rows) per block
#define NT   32          // n-tile (k prototypes) per block
#define LSTR 136         // LDS row stride in bf16 elems (272B, 16B-aligned rows)
#define MIN_NORM 1e-15f

typedef __attribute__((ext_vector_type(8))) short  short8;   // MFMA A/B frag (8 bf16)
typedef __attribute__((ext_vector_type(4))) float  floatx4;  // MFMA C/D frag

static __device__ __forceinline__ unsigned short f2bf(float f) {
    union { float f; unsigned int u; } v; v.f = f;
    unsigned int u = v.u;
    u += 0x7FFFu + ((u >> 16) & 1u);   // round-to-nearest-even
    return (unsigned short)(u >> 16);
}

__global__ __launch_bounds__(256) void mobius_mlr_kernel(
        const float* __restrict__ x, const float* __restrict__ p,
        const float* __restrict__ a, float* __restrict__ out) {
    // 3 x (32 rows x 136 elems x 2B) = 26112 B LDS -> 4+ blocks/CU resident
    __shared__ __align__(16) unsigned short lx[MT * LSTR];
    __shared__ __align__(16) unsigned short lp[NT * LSTR];
    __shared__ __align__(16) unsigned short la[NT * LSTR];
    __shared__ float xsq[MT];                   // |x_b|^2
    __shared__ float p2s[NT], pas[NT], ans[NT]; // |p|^2, p.a, max(||a||,MIN_NORM)

    const int tid = threadIdx.x;
    const int mb0 = blockIdx.x * MT;
    const int nb0 = blockIdx.y * NT;

    // ---- stage tiles: global f32 -> LDS bf16, stats fused into the same pass.
    // Each thread owns 1/8 of one row (4 float4 = 16 elems) of all 3 arrays:
    //   row = tid>>3 (0..31), lanes t8=0..7 cover the row's 32 float4.
    // Loads stay coalesced (8 lanes x 16B = 128B contiguous per row chunk).
    // Stats (|x|^2, |p|^2, p.a, |a|^2) accumulate from the f32 REGISTERS here,
    // so the old LDS-reread + bf2f stats phase (and its barrier) is gone.
    const int row = tid >> 3;
    const int t8  = tid & 7;

    const float4* xg = (const float4*)x + (size_t)mb0 * (D_SZ / 4);
    const float4* pg = (const float4*)p + (size_t)nb0 * (D_SZ / 4);
    const float4* ag = (const float4*)a + (size_t)nb0 * (D_SZ / 4);

    float sx = 0.f, sp = 0.f, spa = 0.f, sa2 = 0.f;
    #pragma unroll
    for (int j = 0; j < 4; ++j) {
        int c4  = t8 + j * 8;                  // 0..31
        int idx = row * (D_SZ / 4) + c4;
        float4 vx = xg[idx];
        float4 vp = pg[idx];
        float4 va = ag[idx];
        sx  += vx.x*vx.x + vx.y*vx.y + vx.z*vx.z + vx.w*vx.w;
        sp  += vp.x*vp.x + vp.y*vp.y + vp.z*vp.z + vp.w*vp.w;
        spa += vp.x*va.x + vp.y*va.y + vp.z*va.z + vp.w*va.w;
        sa2 += va.x*va.x + va.y*va.y + va.z*va.z + va.w*va.w;
        *(ushort4*)&lx[row * LSTR + c4 * 4] =
            make_ushort4(f2bf(vx.x), f2bf(vx.y), f2bf(vx.z), f2bf(vx.w));
        *(ushort4*)&lp[row * LSTR + c4 * 4] =
            make_ushort4(f2bf(vp.x), f2bf(vp.y), f2bf(vp.z), f2bf(vp.w));
        *(ushort4*)&la[row * LSTR + c4 * 4] =
            make_ushort4(f2bf(va.x), f2bf(va.y), f2bf(va.z), f2bf(va.w));
    }
    // reduce across the 8 lanes sharing this row (xor masks stay in-group)
    #pragma unroll
    for (int m = 1; m <= 4; m <<= 1) {
        sx  += __shfl_xor(sx,  m);
        sp  += __shfl_xor(sp,  m);
        spa += __shfl_xor(spa, m);
        sa2 += __shfl_xor(sa2, m);
    }
    if (t8 == 0) {
        xsq[row] = sx;
        p2s[row] = sp;
        pas[row] = spa;
        ans[row] = fmaxf(sqrtf(sa2), MIN_NORM);
    }
    __syncthreads();   // single barrier: tiles + stats both visible

    // ---- MFMA: each wave computes one 16x16 quadrant of both GEMMs ----
    const int lane = tid & 63;
    const int wv   = tid >> 6;
    const int mi   = wv & 1;            // m-quadrant
    const int ni   = wv >> 1;           // n-quadrant
    const int quad = lane >> 4;
    const int r16  = lane & 15;

    floatx4 accp = {0.f, 0.f, 0.f, 0.f};
    floatx4 acca = {0.f, 0.f, 0.f, 0.f};
    #pragma unroll
    for (int dc = 0; dc < 4; ++dc) {
        int d0 = dc * 32 + quad * 8;
        short8 af = *(const short8*)&lx[(mi * 16 + r16) * LSTR + d0];
        short8 bp = *(const short8*)&lp[(ni * 16 + r16) * LSTR + d0];
        short8 ba = *(const short8*)&la[(ni * 16 + r16) * LSTR + d0];
        accp = __builtin_amdgcn_mfma_f32_16x16x32_bf16(af, bp, accp, 0, 0, 0);
        acca = __builtin_amdgcn_mfma_f32_16x16x32_bf16(af, ba, acca, 0, 0, 0);
    }
    // no second __syncthreads needed: stats were written before the barrier,
    // MFMA phase does not touch the stats arrays.

    // ---- fused epilogue ----
    // C/D layout (verified): col = lane&15, row = (lane>>4)*4 + reg
    const int coll = ni * 16 + r16;
    const float p2v = p2s[coll];
    const float pav = pas[coll];
    const float anv = ans[coll];
    float* orow = out + (size_t)(mb0 + mi * 16 + quad * 4) * K_SZ + (nb0 + coll);
    #pragma unroll
    for (int r = 0; r < 4; ++r) {
        float x2v = xsq[mi * 16 + quad * 4 + r];
        float pdx = accp[r];        // p_k . x_b
        float xda = acca[r];        // x_b . a_k
        // mobius_add(-p, x, c=1): xy = -(p.x), x2 = |p|^2, y2 = |x|^2
        float alpha = 1.0f - 2.0f * pdx + x2v;
        float beta  = 1.0f - p2v;
        float den   = fmaxf(1.0f - 2.0f * pdx + p2v * x2v, MIN_NORM);
        float invd  = __builtin_amdgcn_rcpf(den);
        float sqn   = (alpha * alpha * p2v - 2.0f * alpha * beta * pdx
                       + beta * beta * x2v) * invd * invd;   // |mpx|^2
        sqn = fmaxf(sqn, MIN_NORM);
        float mda  = (beta * xda - alpha * pav) * invd;      // mpx . a
        float dden = fmaxf((1.0f - sqn) * anv, MIN_NORM);
        float z    = 2.0f * mda * __builtin_amdgcn_rcpf(dden);
        float dist = __logf(z + sqrtf(z * z + 1.0f));        // asinh(z), z ~ O(0.02)
        orow[r * K_SZ] = 2.0f * anv * dist;
    }
}

extern "C" void kernel_launch(void* const* d_in, const int* in_sizes, int n_in,
                              void* d_out, int out_size, void* d_ws, size_t ws_size,
                              hipStream_t stream) {
    const float* x = (const float*)d_in[0];
    const float* p = (const float*)d_in[1];
    const float* a = (const float*)d_in[2];
    float* out = (float*)d_out;
    dim3 grid(B_SZ / MT, K_SZ / NT);   // (128, 8) = 1024 blocks -> 4 blocks/CU
    mobius_mlr_kernel<<<grid, dim3(256), 0, stream>>>(x, p, a, out);
}